// Round 16
// baseline (609.994 us; speedup 1.0000x reference)
//
#include <hip/hip_runtime.h>
#include <math.h>

// ---- problem constants ----
static constexpr int B_    = 4;
static constexpr int C_    = 192;
static constexpr int NPIX  = 16384;            // 128*128
static constexpr int PTOT  = B_ * NPIX;        // 65536
static constexpr int HEADS = 6;
static constexpr int STR   = 6;
static constexpr int LH    = 22;
static constexpr int LWIN  = LH * LH;          // 484
static constexpr int NWIN  = B_ * LWIN;        // 1936

typedef short bf16x8 __attribute__((ext_vector_type(8)));
typedef float f32x4  __attribute__((ext_vector_type(4)));

// round-half-up bf16 pack (|err| <= 0.5 ulp)
__device__ __forceinline__ unsigned short f2bf(float f) {
    union { float f; unsigned int u; } v; v.f = f;
    return (unsigned short)((v.u + 0x8000u) >> 16);
}
__device__ __forceinline__ float bf2f(unsigned short h) {
    union { unsigned int u; float f; } v; v.u = ((unsigned int)h) << 16;
    return v.f;
}
// pack two floats -> two bf16 in one u32 via v_perm
__device__ __forceinline__ unsigned int pack2bf(float a, float b) {
    union { float f; unsigned int u; } x, y; x.f = a; y.f = b;
    return __builtin_amdgcn_perm(y.u + 0x8000u, x.u + 0x8000u, 0x07060302u);
}
// tanh-form GELU = v * sigmoid(v*(1.59577 + 0.0713548 v^2)); rcp not div
__device__ __forceinline__ float gelu_f(float v) {
    float vv = v * v;
    float u  = v * fmaf(vv, 0.0713548162f, 1.5957691216f);
    float ue = (u > 80.f) ? 80.f : u;
    float e  = __expf(ue);
    float r  = __builtin_amdgcn_rcpf(e + 1.f);
    return v * e * r;
}

// ============================================================
// prep: wgb = bf16(W*g); wsum = sum(W*g); wb = W·bln + bias
// ============================================================
__global__ __launch_bounds__(256) void prep_k(const float* __restrict__ W, const float* __restrict__ g,
                                              const float* __restrict__ bln, const float* __restrict__ bias,
                                              int M, int K,
                                              unsigned short* __restrict__ wgb, float* __restrict__ wsum,
                                              float* __restrict__ wb) {
    int o = blockIdx.x * 256 + threadIdx.x;
    if (o >= M) return;
    float sum = 0.f, bb = 0.f;
    for (int c = 0; c < K; ++c) {
        float wv = W[(size_t)o * K + c];
        float wgv = wv * g[c];
        wgb[(size_t)o * K + c] = f2bf(wgv);
        sum += wgv;
        bb += wv * bln[c];
    }
    wsum[o] = sum;
    wb[o] = bb + bias[o];
}

__global__ __launch_bounds__(256) void wcvt_k(const float* __restrict__ W, unsigned short* __restrict__ Wb, int n) {
    int i = blockIdx.x * 256 + threadIdx.x;
    if (i < n) Wb[i] = f2bf(W[i]);
}

// ============================================================
// MFMA GEMM (gemm4): PIXT=64, integrated staging.
// INMODE 0: Xin = bf16 [b][NPIX][KK] (pre-transposed)
// INMODE 1: Xin = fp32 [b][KK][NPIX]; transpose in staging and
//           compute per-pixel LN stats in-block (LN must be true)
// INMODE 2: Xin = bf16 [b][*][NPIX] channel-major, stride bstride
// SPL: M-split count, encoded in LOW BITS of blockIdx.x so
//      sibling blocks share the pixel tile (L2/L3 locality).
// STATS: per-pixel LN stats over global chunks >= (M/64)/2;
//        written by the sp==SPL-1 block.
// ============================================================
template <int KK, int INMODE, int MPB, int SPL, int ACT, bool LN, bool RES, bool OBF, int STATS>
__global__ __launch_bounds__(256) void gemm4_k(const unsigned short* __restrict__ Wb,
                                               const void* __restrict__ Xin,
                                               void* __restrict__ outv,
                                               const float* __restrict__ wsum, const float* __restrict__ wb,
                                               const float* __restrict__ resid, int M, int bstride,
                                               float* __restrict__ smu, float* __restrict__ srs) {
    constexpr int LDK     = KK + 8;
    constexpr int KSTEPS  = KK / 32;
    constexpr int PFG     = (KSTEPS > 6) ? 6 : KSTEPS;
    __shared__ unsigned short xs[64 * LDK];
    __shared__ float sred[2][4][64];
    __shared__ float muL[64], rsL[64];

    int t = threadIdx.x;
    int bid = blockIdx.x;
    int pt = bid / SPL;
    int sp = bid - pt * SPL;
    int b  = pt >> 8;
    int n0 = (pt & 255) << 6;

    if constexpr (INMODE == 0) {
        const unsigned short* xg = (const unsigned short*)Xin + (size_t)(b * NPIX + n0) * KK;
        constexpr int NJ = KK / 8;
        #pragma unroll
        for (int i = 0; i < 64 * NJ / 256; ++i) {
            int c = i * 256 + t;
            int p, j;
            if (KK == 192) { p = (c * 2731) >> 16; j = c - p * 24; }
            else           { int q = c >> 4; p = (q * 21846) >> 16; j = c - p * 48; }
            uint4 v = *(const uint4*)(xg + (size_t)c * 8);
            *(uint4*)&xs[p * LDK + j * 8] = v;
        }
    } else if constexpr (INMODE == 1) {
        const float* xg = (const float*)Xin + (size_t)b * bstride + n0;
        int px = t & 63, c0 = t >> 6;
        float s = 0.f, s2 = 0.f;
        #pragma unroll 4
        for (int st = 0; st < KK / 4; ++st) {
            int c = c0 + 4 * st;
            float v = xg[(size_t)c * NPIX + px];
            s += v; s2 += v * v;
            xs[px * LDK + c] = f2bf(v);
        }
        sred[0][c0][px] = s;
        sred[1][c0][px] = s2;
        __syncthreads();
        if (t < 64) {
            float ss  = sred[0][0][t] + sred[0][1][t] + sred[0][2][t] + sred[0][3][t];
            float ss2 = sred[1][0][t] + sred[1][1][t] + sred[1][2][t] + sred[1][3][t];
            float m = ss * (1.f / (float)KK);
            muL[t] = m;
            rsL[t] = rsqrtf(ss2 * (1.f / (float)KK) - m * m + 1e-5f);
        }
    } else {
        const unsigned short* xg = (const unsigned short*)Xin + (size_t)b * bstride + n0;
        int px2 = (t & 31) << 1, c0 = t >> 5;
        #pragma unroll 4
        for (int st = 0; st < KK / 8; ++st) {
            int c = c0 + 8 * st;
            unsigned int v = *(const unsigned int*)(xg + (size_t)c * NPIX + px2);
            xs[px2 * LDK + c]       = (unsigned short)(v & 0xFFFFu);
            xs[(px2 + 1) * LDK + c] = (unsigned short)(v >> 16);
        }
    }
    __syncthreads();

    int w  = t >> 6, l = t & 63;
    int wr = w >> 1, wc = w & 1;
    int lr = l & 15, kb = l >> 4;
    int pw = wr * 32;

    bf16x8 afr[KSTEPS][2];
    #pragma unroll
    for (int ks = 0; ks < KSTEPS; ++ks)
        #pragma unroll
        for (int m = 0; m < 2; ++m)
            afr[ks][m] = *(const bf16x8*)&xs[(pw + m * 16 + lr) * LDK + ks * 32 + kb * 8];

    float rsv[2][4], murs[2][4];
    if (LN) {
        #pragma unroll
        for (int m = 0; m < 2; ++m) {
            int pl = pw + m * 16 + kb * 4;
            #pragma unroll
            for (int r = 0; r < 4; ++r) {
                float mv = muL[pl + r];
                rsv[m][r] = rsL[pl + r];
                murs[m][r] = mv * rsv[m][r];
            }
        }
    }

    float zs[2][4], zs2[2][4];
    if constexpr (STATS) {
        #pragma unroll
        for (int m = 0; m < 2; ++m)
            #pragma unroll
            for (int r = 0; r < 4; ++r) { zs[m][r] = 0.f; zs2[m][r] = 0.f; }
    }

    int ocbase = sp * MPB;
    int halfM = (M >> 6) >> 1;
    #pragma unroll 2
    for (int oc = 0; oc < MPB; ++oc) {
        int ow = ((ocbase + oc) << 6) + wc * 32;
        f32x4 acc[2][2];
        #pragma unroll
        for (int m = 0; m < 2; ++m)
            #pragma unroll
            for (int n = 0; n < 2; ++n) acc[m][n] = (f32x4){0.f, 0.f, 0.f, 0.f};

        #pragma unroll
        for (int kg = 0; kg < KSTEPS; kg += PFG) {
            bf16x8 bfr[PFG][2];
            #pragma unroll
            for (int kk = 0; kk < PFG; ++kk)
                #pragma unroll
                for (int n = 0; n < 2; ++n)
                    bfr[kk][n] = *(const bf16x8*)(Wb + (size_t)(ow + n * 16 + lr) * KK + (kg + kk) * 32 + kb * 8);
            #pragma unroll
            for (int kk = 0; kk < PFG; ++kk)
                #pragma unroll
                for (int m = 0; m < 2; ++m)
                    #pragma unroll
                    for (int n = 0; n < 2; ++n)
                        acc[m][n] = __builtin_amdgcn_mfma_f32_16x16x32_bf16(afr[kg + kk][m], bfr[kk][n], acc[m][n], 0, 0, 0);
        }

        #pragma unroll
        for (int m = 0; m < 2; ++m) {
            int nidx = n0 + pw + m * 16 + kb * 4;
            #pragma unroll
            for (int n = 0; n < 2; ++n) {
                int o = ow + n * 16 + lr;
                float wbv = wb[o];
                float wsv = 0.f; if (LN) wsv = wsum[o];
                size_t obase = (((size_t)b * M + o) << 14) + nidx;
                float rv[4] = {0.f, 0.f, 0.f, 0.f};
                if (RES) {
                    float4 rr = *(const float4*)(resid + obase);
                    rv[0] = rr.x; rv[1] = rr.y; rv[2] = rr.z; rv[3] = rr.w;
                }
                float vo[4];
                #pragma unroll
                for (int r = 0; r < 4; ++r) {
                    float a = acc[m][n][r];
                    float v;
                    if (LN) { float t1 = fmaf(-murs[m][r], wsv, wbv); v = fmaf(rsv[m][r], a, t1); }
                    else    v = a + wbv;
                    if (ACT == 1) v = gelu_f(v);
                    vo[r] = v + rv[r];
                    if constexpr (STATS) {
                        if (ocbase + oc >= halfM) { zs[m][r] += vo[r]; zs2[m][r] += vo[r] * vo[r]; }
                    }
                }
                if (OBF) {
                    uint2 u;
                    u.x = pack2bf(vo[0], vo[1]);
                    u.y = pack2bf(vo[2], vo[3]);
                    *(uint2*)((unsigned short*)outv + obase) = u;
                } else {
                    float4 f = {vo[0], vo[1], vo[2], vo[3]};
                    *(float4*)((float*)outv + obase) = f;
                }
            }
        }
    }

    if constexpr (STATS) {
        if (sp == SPL - 1) {
            __shared__ float sst[64][2][2];
            #pragma unroll
            for (int m = 0; m < 2; ++m)
                #pragma unroll
                for (int r = 0; r < 4; ++r) {
                    float a  = zs[m][r], c2 = zs2[m][r];
                    a  += __shfl_xor(a, 1);  a  += __shfl_xor(a, 2);  a  += __shfl_xor(a, 4);  a  += __shfl_xor(a, 8);
                    c2 += __shfl_xor(c2, 1); c2 += __shfl_xor(c2, 2); c2 += __shfl_xor(c2, 4); c2 += __shfl_xor(c2, 8);
                    if (lr == 0) {
                        int pp = pw + m * 16 + kb * 4 + r;
                        sst[pp][wc][0] = a; sst[pp][wc][1] = c2;
                    }
                }
            __syncthreads();
            if (t < 64) {
                float ss  = sst[t][0][0] + sst[t][1][0];
                float ss2 = sst[t][0][1] + sst[t][1][1];
                float invC = 2.f / (float)M;
                float mm = ss * invC;
                smu[(b << 14) + n0 + t] = mm;
                srs[(b << 14) + n0 + t] = rsqrtf(ss2 * invC - mm * mm + 1e-5f);
            }
        }
    }
}

// ============================================================
// MFMA attention (o_win bf16)
// ============================================================
__global__ __launch_bounds__(64) void attn_mfma_k(const unsigned short* __restrict__ qkv,
                                                  const float* __restrict__ rpb,
                                                  const float* __restrict__ temp,
                                                  unsigned short* __restrict__ o_win,
                                                  float* __restrict__ s_win) {
    __shared__ unsigned short p_lds[64 * 72];
    __shared__ float rp[225];
    int wh = blockIdx.x;
    int head = wh % HEADS;
    int bw = wh / HEADS;
    int b = bw / LWIN, l = bw % LWIN;
    int sh = l / LH, sw = l % LH;
    int h0 = sh * STR - 3, w0 = sw * STR - 3;
    int t = threadIdx.x;
    int lr = t & 15, kb = t >> 4;

    for (int i = t; i < 225; i += 64) rp[i] = rpb[i * HEADS + head];
    float tmp = temp[head];

    const size_t qbase = ((size_t)(b * 576 + head * 32)) << 14;
    const unsigned short* qp = qkv + qbase;
    const unsigned short* kp = qkv + qbase + ((size_t)192 << 14);
    const unsigned short* vp = qkv + qbase + ((size_t)384 << 14);

    bf16x8 kf[4], qf[4];
    #pragma unroll
    for (int m = 0; m < 4; ++m) {
        int jp = m * 16 + lr;
        int hh = h0 + (jp >> 3), ww = w0 + (jp & 7);
        bool ok = ((unsigned)hh < 128u) && ((unsigned)ww < 128u);
        int pix = (hh << 7) + ww;
        #pragma unroll
        for (int j = 0; j < 8; ++j) {
            unsigned short kv = 0, qv = 0;
            if (ok) {
                size_t off = ((size_t)(kb * 8 + j) << 14) + pix;
                kv = kp[off];
                qv = qp[off];
            }
            kf[m][j] = (short)kv;
            qf[m][j] = (short)qv;
        }
    }

    f32x4 st[4][4];
    #pragma unroll
    for (int m = 0; m < 4; ++m)
        #pragma unroll
        for (int n = 0; n < 4; ++n) st[m][n] = (f32x4){0.f, 0.f, 0.f, 0.f};
    #pragma unroll
    for (int m = 0; m < 4; ++m)
        #pragma unroll
        for (int n = 0; n < 4; ++n)
            st[m][n] = __builtin_amdgcn_mfma_f32_16x16x32_bf16(kf[m], qf[n], st[m][n], 0, 0, 0);

    bf16x8 vf[2][2];
    #pragma unroll
    for (int np = 0; np < 2; ++np) {
        #pragma unroll
        for (int ks = 0; ks < 2; ++ks) {
            int hh = h0 + ks * 4 + kb;
            bool okr = (unsigned)hh < 128u;
            const unsigned short* vrow = vp + (((size_t)(np * 16 + lr)) << 14) + (hh << 7) + w0;
            #pragma unroll
            for (int j = 0; j < 8; ++j) {
                int ww = w0 + j;
                unsigned short vv = 0;
                if (okr && (unsigned)ww < 128u) vv = vrow[j];
                vf[np][ks][j] = (short)vv;
            }
        }
    }

    __syncthreads();

    #pragma unroll
    for (int n = 0; n < 4; ++n) {
        int i = n * 16 + lr;
        int iyy = i >> 3, ixx = i & 7;
        #pragma unroll
        for (int m = 0; m < 4; ++m) {
            #pragma unroll
            for (int r = 0; r < 4; ++r) {
                int j = m * 16 + kb * 4 + r;
                int dy = iyy - (j >> 3) + 7;
                int dx = ixx - (j & 7) + 7;
                st[m][n][r] = st[m][n][r] * tmp + rp[dy * 15 + dx];
            }
        }
    }

    #pragma unroll
    for (int n = 0; n < 4; ++n) {
        float mx = -1e30f;
        #pragma unroll
        for (int m = 0; m < 4; ++m)
            #pragma unroll
            for (int r = 0; r < 4; ++r) mx = fmaxf(mx, st[m][n][r]);
        mx = fmaxf(mx, __shfl_xor(mx, 16));
        mx = fmaxf(mx, __shfl_xor(mx, 32));
        float s = 0.f;
        #pragma unroll
        for (int m = 0; m < 4; ++m) {
            #pragma unroll
            for (int r = 0; r < 4; ++r) {
                float e = __expf(st[m][n][r] - mx);
                st[m][n][r] = e;
                s += e;
            }
        }
        s += __shfl_xor(s, 16);
        s += __shfl_xor(s, 32);
        int i = n * 16 + lr;
        if (kb == 0) s_win[(size_t)wh * 64 + i] = s;
        #pragma unroll
        for (int m = 0; m < 4; ++m) {
            *(unsigned int*)&p_lds[i * 72 + m * 16 + kb * 4]     = pack2bf(st[m][n][0], st[m][n][1]);
            *(unsigned int*)&p_lds[i * 72 + m * 16 + kb * 4 + 2] = pack2bf(st[m][n][2], st[m][n][3]);
        }
    }

    __syncthreads();

    f32x4 oc[4][2];
    #pragma unroll
    for (int m = 0; m < 4; ++m)
        #pragma unroll
        for (int np = 0; np < 2; ++np) oc[m][np] = (f32x4){0.f, 0.f, 0.f, 0.f};
    #pragma unroll
    for (int ks = 0; ks < 2; ++ks) {
        bf16x8 pa[4];
        #pragma unroll
        for (int m = 0; m < 4; ++m)
            pa[m] = *(const bf16x8*)&p_lds[(m * 16 + lr) * 72 + ks * 32 + kb * 8];
        #pragma unroll
        for (int m = 0; m < 4; ++m)
            #pragma unroll
            for (int np = 0; np < 2; ++np)
                oc[m][np] = __builtin_amdgcn_mfma_f32_16x16x32_bf16(pa[m], vf[np][ks], oc[m][np], 0, 0, 0);
    }

    unsigned short* ob = o_win + (size_t)wh * 2048;
    #pragma unroll
    for (int m = 0; m < 4; ++m) {
        int ibase = m * 16 + kb * 4;
        #pragma unroll
        for (int np = 0; np < 2; ++np) {
            int c = np * 16 + lr;
            #pragma unroll
            for (int r = 0; r < 4; ++r)
                ob[(ibase + r) * 32 + c] = f2bf(oc[m][np][r]);
        }
    }
}

// ============================================================
__device__ __forceinline__ void win_range(int h, int& s0, int& s1) {
    s0 = (h + 1) / 6; if (s0 < 0) s0 = 0;
    s1 = (h + 3) / 6; if (s1 > 21) s1 = 21;
}

__global__ __launch_bounds__(256) void simg_k(const float* __restrict__ s_win, float* __restrict__ s_img) {
    int tid = blockIdx.x * 256 + threadIdx.x;
    if (tid >= B_ * HEADS * NPIX) return;
    int n = tid & (NPIX - 1);
    int bh = tid >> 14;
    int hd = bh % HEADS, b = bh / HEADS;
    int hy = n >> 7, wx = n & 127;
    int sy0, sy1, sx0, sx1;
    win_range(hy, sy0, sy1);
    win_range(wx, sx0, sx1);
    float acc = 0.f;
    for (int sy = sy0; sy <= sy1; ++sy)
        for (int sx = sx0; sx <= sx1; ++sx) {
            int idx = (hy - (sy * 6 - 3)) * 8 + (wx - (sx * 6 - 3));
            acc += s_win[(size_t)((b * LWIN + sy * LH + sx) * HEADS + hd) * 64 + idx];
        }
    s_img[tid] = acc;
}

// ============================================================
// fused fold + proj GEMM: block = 64 px.
// ============================================================
__global__ __launch_bounds__(256) void fold_proj_k(const unsigned short* __restrict__ o_win,
                                                   const float* __restrict__ s_img,
                                                   const unsigned short* __restrict__ Wb,
                                                   const float* __restrict__ wb,
                                                   unsigned short* __restrict__ outv) {
    constexpr int KK = 192, LDK = 200, KSTEPS = 6, PFG = 6, MPB = 3;
    __shared__ unsigned short xs[64 * LDK];

    int t = threadIdx.x;
    int pt = blockIdx.x;
    int b  = pt >> 8;
    int n0 = (pt & 255) << 6;

    // ---- phase 1: fold into LDS ----
    #pragma unroll
    for (int it = 0; it < 6; ++it) {
        int item = it * 256 + t;                 // < 1536
        int px = (item * 2731) >> 16;            // item / 24
        int oct = item - px * 24;
        int n = n0 + px;
        int hd = oct >> 2, c8 = (oct & 3) << 3;
        int hy = n >> 7, wx = n & 127;
        int sy0, sy1, sx0, sx1;
        win_range(hy, sy0, sy1);
        win_range(wx, sx0, sx1);
        float acc[8] = {0.f, 0.f, 0.f, 0.f, 0.f, 0.f, 0.f, 0.f};
        for (int sy = sy0; sy <= sy1; ++sy)
            for (int sx = sx0; sx <= sx1; ++sx) {
                int idx = (hy - (sy * 6 - 3)) * 8 + (wx - (sx * 6 - 3));
                const unsigned short* p = o_win + ((size_t)((b * LWIN + sy * LH + sx) * HEADS + hd) * 2048 + idx * 32 + c8);
                uint4 v = *(const uint4*)p;
                unsigned int arr[4] = {v.x, v.y, v.z, v.w};
                #pragma unroll
                for (int j = 0; j < 4; ++j) {
                    acc[2 * j]     += bf2f((unsigned short)(arr[j] & 0xFFFFu));
                    acc[2 * j + 1] += bf2f((unsigned short)(arr[j] >> 16));
                }
            }
        float inv = __builtin_amdgcn_rcpf(s_img[((b * HEADS + hd) << 14) + n]);
        unsigned int pk[4];
        #pragma unroll
        for (int j = 0; j < 4; ++j)
            pk[j] = pack2bf(acc[2 * j] * inv, acc[2 * j + 1] * inv);
        *(uint4*)&xs[px * LDK + hd * 32 + c8] = make_uint4(pk[0], pk[1], pk[2], pk[3]);
    }
    __syncthreads();

    // ---- phase 2: proj MFMA ----
    int w  = t >> 6, l = t & 63;
    int wr = w >> 1, wc = w & 1;
    int lr = l & 15, kb = l >> 4;
    int pw = wr * 32;

    bf16x8 afr[KSTEPS][2];
    #pragma unroll
    for (int ks = 0; ks < KSTEPS; ++ks)
        #pragma unroll
        for (int m = 0; m < 2; ++m)
            afr[ks][m] = *(const bf16x8*)&xs[(pw + m * 16 + lr) * LDK + ks * 32 + kb * 8];

    #pragma unroll
    for (int oc = 0; oc < MPB; ++oc) {
        int ow = (oc << 6) + wc * 32;
        f32x4 acc2[2][2];
        #pragma unroll
        for (int m = 0; m < 2; ++m)
            #pragma unroll
            for (int n = 0; n < 2; ++n) acc2[m][n] = (f32x4){0.f, 0.f, 0.f, 0.f};

        #pragma unroll
        for (int kg = 0; kg < KSTEPS; kg += PFG) {
            bf16x8 bfr[PFG][2];
            #pragma unroll
            for (int kk = 0; kk < PFG; ++kk)
                #pragma unroll
                for (int n = 0; n < 2; ++n)
                    bfr[kk][n] = *(const bf16x8*)(Wb + (size_t)(ow + n * 16 + lr) * KK + (kg + kk) * 32 + kb * 8);
            #pragma unroll
            for (int kk = 0; kk < PFG; ++kk)
                #pragma unroll
                for (int m = 0; m < 2; ++m)
                    #pragma unroll
                    for (int n = 0; n < 2; ++n)
                        acc2[m][n] = __builtin_amdgcn_mfma_f32_16x16x32_bf16(afr[kg + kk][m], bfr[kk][n], acc2[m][n], 0, 0, 0);
        }

        #pragma unroll
        for (int m = 0; m < 2; ++m) {
            int nidx = n0 + pw + m * 16 + kb * 4;
            #pragma unroll
            for (int n = 0; n < 2; ++n) {
                int o = ow + n * 16 + lr;
                float wbv = wb[o];
                size_t obase = (((size_t)b * 192 + o) << 14) + nidx;
                uint2 u;
                u.x = pack2bf(acc2[m][n][0] + wbv, acc2[m][n][1] + wbv);
                u.y = pack2bf(acc2[m][n][2] + wbv, acc2[m][n][3] + wbv);
                *(uint2*)(outv + obase) = u;
            }
        }
    }
}

// ============================================================
// 2x2 average pooling (input fp32 or bf16, output fp32)
// ============================================================
template <typename TI>
__global__ __launch_bounds__(256) void halve_k(const TI* __restrict__ in, float* __restrict__ out, int Win) {
    int Wo = Win >> 1;
    int tot = B_ * C_ * Wo * Wo;
    int tid = blockIdx.x * 256 + threadIdx.x;
    if (tid >= tot) return;
    int xy = tid % (Wo * Wo);
    int bc = tid / (Wo * Wo);
    int y = xy / Wo, x = xy % Wo;
    const TI* p = in + (size_t)bc * Win * Win + (size_t)(2 * y) * Win + 2 * x;
    float a, bq, c, d;
    if constexpr (sizeof(TI) == 2) {
        a = bf2f(p[0]); bq = bf2f(p[1]); c = bf2f(p[Win]); d = bf2f(p[Win + 1]);
    } else {
        a = p[0]; bq = p[1]; c = p[Win]; d = p[Win + 1];
    }
    out[tid] = 0.25f * (a + bq + c + d);
}

// ============================================================
// fused HFT (po bf16)
// ============================================================
__global__ __launch_bounds__(256) void hft_fused_k(const unsigned short* __restrict__ po, const float* __restrict__ x,
                                                   const float* __restrict__ p2, const float* __restrict__ p4,
                                                   const float* __restrict__ p8, const float* __restrict__ hw,
                                                   const float* __restrict__ hb, float* __restrict__ x1) {
    __shared__ float tile[34 * 133];
    int rt = blockIdx.x, ch = blockIdx.y, b = blockIdx.z;
    int bc = b * C_ + ch;
    int y0 = rt << 5;
    int t = threadIdx.x;
    const unsigned short* pob = po + ((size_t)bc << 14);
    const float* p2b = p2 + ((size_t)bc << 12);
    const float* p4b = p4 + ((size_t)bc << 10);
    const float* p8b = p8 + ((size_t)bc << 8);

    for (int idx = t; idx < 34 * 133; idx += 256) {
        int row = idx / 133, col = idx - row * 133;
        int yy = y0 + row - 1, xw = col - 1;
        float val = 0.f;
        if (col < 130 && (unsigned)yy < 128u && (unsigned)xw < 128u) {
            int nn = (yy << 7) + xw;
            val = 3.f * bf2f(pob[nn])
                - p2b[((yy >> 1) << 6) + (xw >> 1)]
                - p4b[((yy >> 2) << 5) + (xw >> 2)]
                - p8b[((yy >> 3) << 4) + (xw >> 3)];
        }
        tile[idx] = val;
    }
    __syncthreads();

    float wv[9];
    #pragma unroll
    for (int k = 0; k < 9; ++k) wv[k] = hw[ch * 9 + k];
    float hbv = hb[ch];

    int r = t & 31, c0 = (t >> 5) << 4;
    int nbase = ((y0 + r) << 7) + c0;
    const float* xb = x + ((size_t)bc << 14);
    float* x1b = x1 + ((size_t)bc << 14);

    float pov[16], xv[16];
    {
        const uint4* pp4 = (const uint4*)(pob + nbase);
        uint4 a0 = pp4[0], a1 = pp4[1];
        unsigned int arr[8] = {a0.x, a0.y, a0.z, a0.w, a1.x, a1.y, a1.z, a1.w};
        #pragma unroll
        for (int j = 0; j < 8; ++j) {
            pov[2 * j]     = bf2f((unsigned short)(arr[j] & 0xFFFFu));
            pov[2 * j + 1] = bf2f((unsigned short)(arr[j] >> 16));
        }
        #pragma unroll
        for (int j4 = 0; j4 < 4; ++j4) {
            float4 xx = *(const float4*)(xb + nbase + 4 * j4);
            xv[4*j4] = xx.x; xv[4*j4+1] = xx.y; xv[4*j4+2] = xx.z; xv[4*j4+3] = xx.w;
        }
    }
    float res[16];
    #pragma unroll
    for (int j = 0; j < 16; ++j) {
        float acc = hbv;
        #pragma unroll
        for (int dy = 0; dy < 3; ++dy)
            #pragma unroll
            for (int dx = 0; dx < 3; ++dx)
                acc += wv[dy * 3 + dx] * tile[(r + dy) * 133 + c0 + j + dx];
        float sg = __builtin_amdgcn_rcpf(1.f + __expf(-acc));
        res[j] = xv[j] + sg * pov[j];
    }
    #pragma unroll
    for (int j4 = 0; j4 < 4; ++j4) {
        float4 o = {res[4*j4], res[4*j4+1], res[4*j4+2], res[4*j4+3]};
        *(float4*)(x1b + nbase + 4 * j4) = o;
    }
}

// ============================================================
// SimpleGate tiled
// ============================================================
__global__ __launch_bounds__(256) void sgmul_k(unsigned short* __restrict__ z,
                                               const float* __restrict__ mu3, const float* __restrict__ rs3,
                                               const float* __restrict__ sgn_g, const float* __restrict__ sgn_b,
                                               const float* __restrict__ sg_w, const float* __restrict__ sg_b) {
    __shared__ float tile[34 * 133];
    int rt = blockIdx.x, ch = blockIdx.y, b = blockIdx.z;
    int y0 = rt << 5;
    int t = threadIdx.x;
    const unsigned short* zb = z + ((size_t)(b * 768 + 384 + ch) << 14);
    unsigned short* z1p = z + ((size_t)(b * 768 + ch) << 14);
    const float* mub = mu3 + (b << 14);
    const float* rsb = rs3 + (b << 14);
    float g = sgn_g[ch], bb = sgn_b[ch];

    for (int idx = t; idx < 34 * 133; idx += 256) {
        int row = idx / 133, col = idx - row * 133;
        int yy = y0 + row - 1, xw = col - 1;
        float val = 0.f;
        if (col < 130 && (unsigned)yy < 128u && (unsigned)xw < 128u) {
            int nn = (yy << 7) + xw;
            val = (bf2f(zb[nn]) - mub[nn]) * rsb[nn] * g + bb;
        }
        tile[idx] = val;
    }
    __syncthreads();

    float wv[9];
    #pragma unroll
    for (int k = 0; k < 9; ++k) wv[k] = sg_w[ch * 9 + k];
    float sb = sg_b[ch];

    int r = t & 31, c0 = (t >> 5) << 4;
    int nbase = ((y0 + r) << 7) + c0;

    float res[16];
    #pragma unroll
    for (int j = 0; j < 16; ++j) {
        float acc = sb;
        #pragma unroll
        for (int dy = 0; dy < 3; ++dy)
            #pragma unroll
            for (int dx = 0; dx < 3; ++dx)
                acc += wv[dy * 3 + dx] * tile[(r + dy) * 133 + c0 + j + dx];
        res[j] = acc;
    }
    uint4* zp = (uint4*)(z1p + nbase);
    uint4 v0 = zp[0], v1 = zp[1];
    unsigned int arr[8] = {v0.x, v0.y, v0.z, v0.w, v1.x, v1.y, v1.z, v1.w};
    #pragma unroll
    for (int j = 0; j < 8; ++j) {
        float lo = bf2f((unsigned short)(arr[j] & 0xFFFFu)) * res[2 * j];
        float hi = bf2f((unsigned short)(arr[j] >> 16)) * res[2 * j + 1];
        arr[j] = pack2bf(lo, hi);
    }
    zp[0] = make_uint4(arr[0], arr[1], arr[2], arr[3]);
    zp[1] = make_uint4(arr[4], arr[5], arr[6], arr[7]);
}

// ============================================================
extern "C" void kernel_launch(void* const* d_in, const int* in_sizes, int n_in,
                              void* d_out, int out_size, void* d_ws, size_t ws_size,
                              hipStream_t stream) {
    const float* x     = (const float*)d_in[0];
    const float* n1g   = (const float*)d_in[1];
    const float* n1b   = (const float*)d_in[2];
    const float* qkv_w = (const float*)d_in[3];
    const float* qkv_b = (const float*)d_in[4];
    const float* temp  = (const float*)d_in[5];
    const float* rpb   = (const float*)d_in[6];
    const float* proj_w= (const float*)d_in[7];
    const float* proj_b= (const float*)d_in[8];
    const float* hft_w = (const float*)d_in[9];
    const float* hft_b = (const float*)d_in[10];
    const float* n2g   = (const float*)d_in[11];
    const float* n2b   = (const float*)d_in[12];
    const float* fc1_w = (const float*)d_in[13];
    const float* fc1_b = (const float*)d_in[14];
    const float* sgn_g = (const float*)d_in[15];
    const float* sgn_b = (const float*)d_in[16];
    const float* sg_w  = (const float*)d_in[17];
    const float* sg_b  = (const float*)d_in[18];
    const float* fc2_w = (const float*)d_in[19];
    const float* fc2_b = (const float*)d_in[20];
    float* out = (float*)d_out;
    float* w = (float*)d_ws;

    // ---- workspace layout ----
    float* mu3 = w + 262144;   float* rs3 = w + 327680;
    unsigned short* wgb_qkv = (unsigned short*)(w + 393216);
    float* wsum_qkv = w + 448512;  float* wb_qkv = w + 449088;
    unsigned short* wgb_fc1 = (unsigned short*)(w + 449664);
    float* wsum_fc1 = w + 523392;  float* wb_fc1 = w + 524160;
    unsigned short* pwb  = (unsigned short*)(w + 524928);
    unsigned short* f2wb = (unsigned short*)(w + 543360);
    unsigned short* qkvb = (unsigned short*)(w + 6871680);
    unsigned short* proj_out = (unsigned short*)(w + 580224);  // bf16 [b][192][NPIX]
    float* p2 = w + 19454592;  float* p4 = w + 22600320;  float* p8 = w + 23386752;
    unsigned short* o_win = (unsigned short*)(w + 25746048);
    float* s_win = w + 49535616;
    float* s_img = w + 50279040;
    unsigned short* z = (unsigned short*)(w + 25746048);
    float* x1 = w + 50911872;

    // ---- stage A: prep + qkv GEMM (LN in-block from fp32 x) ----
    prep_k<<<3, 256, 0, stream>>>(qkv_w, n1g, n1b, qkv_b, 576, 192, wgb_qkv, wsum_qkv, wb_qkv);
    wcvt_k<<<144, 256, 0, stream>>>(proj_w, pwb, 192 * 192);
    gemm4_k<192, 1, 9, 1, 0, true, false, true, 0><<<dim3(1024, 1), 256, 0, stream>>>(
        wgb_qkv, x, qkvb, wsum_qkv, wb_qkv, nullptr, 576, 192 * NPIX, nullptr, nullptr);
    // ---- stage B: MFMA window attention ----
    attn_mfma_k<<<NWIN * HEADS, 64, 0, stream>>>(qkvb, rpb, temp, o_win, s_win);
    // ---- stage C+D: simg + fused fold/proj -> proj_out bf16 ----
    simg_k<<<1536, 256, 0, stream>>>(s_win, s_img);
    fold_proj_k<<<1024, 256, 0, stream>>>(o_win, s_img, pwb, proj_b, proj_out);
    // ---- stage E: HFT + residual -> x1 (fused) ----
    halve_k<unsigned short><<<12288, 256, 0, stream>>>(proj_out, p2, 128);
    halve_k<float><<<3072, 256, 0, stream>>>(p2, p4, 64);
    halve_k<float><<<768, 256, 0, stream>>>(p4, p8, 32);
    hft_fused_k<<<dim3(4, 192, B_), 256, 0, stream>>>(proj_out, x, p2, p4, p8, hft_w, hft_b, x1);
    // ---- stage F: prep + fc1 GEMM (LN in-block, SPLIT=2 low-bit, z2 stats) ----
    prep_k<<<3, 256, 0, stream>>>(fc1_w, n2g, n2b, fc1_b, 768, 192, wgb_fc1, wsum_fc1, wb_fc1);
    gemm4_k<192, 1, 6, 2, 1, true, false, true, 1><<<dim3(2048, 1), 256, 0, stream>>>(
        wgb_fc1, x1, z, wsum_fc1, wb_fc1, nullptr, 768, 192 * NPIX, mu3, rs3);
    // ---- stage G: SimpleGate (in-place on z1 rows) ----
    sgmul_k<<<dim3(4, 384, B_), 256, 0, stream>>>(z, mu3, rs3, sgn_g, sgn_b, sg_w, sg_b);
    // ---- stage H: fc2 GEMM (channel-major bf16 in) + residual -> out ----
    wcvt_k<<<288, 256, 0, stream>>>(fc2_w, f2wb, 192 * 384);
    gemm4_k<384, 2, 3, 1, 0, false, true, false, 0><<<dim3(1024, 1), 256, 0, stream>>>(
        f2wb, z, out, nullptr, fc2_b, x1, 192, 768 * NPIX, nullptr, nullptr);
}

// Round 17
// 597.082 us; speedup vs baseline: 1.0216x; 1.0216x over previous
//
#include <hip/hip_runtime.h>
#include <math.h>

// ---- problem constants ----
static constexpr int B_    = 4;
static constexpr int C_    = 192;
static constexpr int NPIX  = 16384;            // 128*128
static constexpr int PTOT  = B_ * NPIX;        // 65536
static constexpr int HEADS = 6;
static constexpr int STR   = 6;
static constexpr int LH    = 22;
static constexpr int LWIN  = LH * LH;          // 484
static constexpr int NWIN  = B_ * LWIN;        // 1936

typedef short bf16x8 __attribute__((ext_vector_type(8)));
typedef float f32x4  __attribute__((ext_vector_type(4)));

// round-half-up bf16 pack (|err| <= 0.5 ulp)
__device__ __forceinline__ unsigned short f2bf(float f) {
    union { float f; unsigned int u; } v; v.f = f;
    return (unsigned short)((v.u + 0x8000u) >> 16);
}
__device__ __forceinline__ float bf2f(unsigned short h) {
    union { unsigned int u; float f; } v; v.u = ((unsigned int)h) << 16;
    return v.f;
}
// pack two floats -> two bf16 in one u32 via v_perm
__device__ __forceinline__ unsigned int pack2bf(float a, float b) {
    union { float f; unsigned int u; } x, y; x.f = a; y.f = b;
    return __builtin_amdgcn_perm(y.u + 0x8000u, x.u + 0x8000u, 0x07060302u);
}
// tanh-form GELU = v * sigmoid(v*(1.59577 + 0.0713548 v^2)); rcp not div
__device__ __forceinline__ float gelu_f(float v) {
    float vv = v * v;
    float u  = v * fmaf(vv, 0.0713548162f, 1.5957691216f);
    float ue = (u > 80.f) ? 80.f : u;
    float e  = __expf(ue);
    float r  = __builtin_amdgcn_rcpf(e + 1.f);
    return v * e * r;
}

// ============================================================
// prep: wgb = bf16(W*g); wsum = sum(W*g); wb = W·bln + bias
// ============================================================
__global__ __launch_bounds__(256) void prep_k(const float* __restrict__ W, const float* __restrict__ g,
                                              const float* __restrict__ bln, const float* __restrict__ bias,
                                              int M, int K,
                                              unsigned short* __restrict__ wgb, float* __restrict__ wsum,
                                              float* __restrict__ wb) {
    int o = blockIdx.x * 256 + threadIdx.x;
    if (o >= M) return;
    float sum = 0.f, bb = 0.f;
    for (int c = 0; c < K; ++c) {
        float wv = W[(size_t)o * K + c];
        float wgv = wv * g[c];
        wgb[(size_t)o * K + c] = f2bf(wgv);
        sum += wgv;
        bb += wv * bln[c];
    }
    wsum[o] = sum;
    wb[o] = bb + bias[o];
}

__global__ __launch_bounds__(256) void wcvt_k(const float* __restrict__ W, unsigned short* __restrict__ Wb, int n) {
    int i = blockIdx.x * 256 + threadIdx.x;
    if (i < n) Wb[i] = f2bf(W[i]);
}

// ============================================================
// MFMA GEMM (gemm4): PIXT=64, integrated staging.
// INMODE 0: Xin = bf16 [b][NPIX][KK] (pre-transposed)
// INMODE 1: Xin = fp32 [b][KK][NPIX]; transpose in staging and
//           compute per-pixel LN stats in-block (LN must be true)
// INMODE 2: Xin = bf16 [b][*][NPIX] channel-major, stride bstride
// STATS: accumulate per-pixel LN stats over chunks >= MPB/2
//        (requires gridDim.y == 1) -> smu/srs
// ============================================================
template <int KK, int INMODE, int MPB, int ACT, bool LN, bool RES, bool OBF, int STATS>
__global__ __launch_bounds__(256) void gemm4_k(const unsigned short* __restrict__ Wb,
                                               const void* __restrict__ Xin,
                                               void* __restrict__ outv,
                                               const float* __restrict__ wsum, const float* __restrict__ wb,
                                               const float* __restrict__ resid, int M, int bstride,
                                               float* __restrict__ smu, float* __restrict__ srs) {
    constexpr int LDK     = KK + 8;
    constexpr int KSTEPS  = KK / 32;
    constexpr int PFG     = (KSTEPS > 6) ? 6 : KSTEPS;
    __shared__ unsigned short xs[64 * LDK];
    __shared__ float sred[2][4][64];
    __shared__ float muL[64], rsL[64];

    int t = threadIdx.x;
    int pt = blockIdx.x;
    int b  = pt >> 8;
    int n0 = (pt & 255) << 6;

    if constexpr (INMODE == 0) {
        const unsigned short* xg = (const unsigned short*)Xin + (size_t)(b * NPIX + n0) * KK;
        constexpr int NJ = KK / 8;
        #pragma unroll
        for (int i = 0; i < 64 * NJ / 256; ++i) {
            int c = i * 256 + t;
            int p, j;
            if (KK == 192) { p = (c * 2731) >> 16; j = c - p * 24; }
            else           { int q = c >> 4; p = (q * 21846) >> 16; j = c - p * 48; }
            uint4 v = *(const uint4*)(xg + (size_t)c * 8);
            *(uint4*)&xs[p * LDK + j * 8] = v;
        }
    } else if constexpr (INMODE == 1) {
        const float* xg = (const float*)Xin + (size_t)b * bstride + n0;
        int px = t & 63, c0 = t >> 6;
        float s = 0.f, s2 = 0.f;
        #pragma unroll 4
        for (int st = 0; st < KK / 4; ++st) {
            int c = c0 + 4 * st;
            float v = xg[(size_t)c * NPIX + px];
            s += v; s2 += v * v;
            xs[px * LDK + c] = f2bf(v);
        }
        sred[0][c0][px] = s;
        sred[1][c0][px] = s2;
        __syncthreads();
        if (t < 64) {
            float ss  = sred[0][0][t] + sred[0][1][t] + sred[0][2][t] + sred[0][3][t];
            float ss2 = sred[1][0][t] + sred[1][1][t] + sred[1][2][t] + sred[1][3][t];
            float m = ss * (1.f / (float)KK);
            muL[t] = m;
            rsL[t] = rsqrtf(ss2 * (1.f / (float)KK) - m * m + 1e-5f);
        }
    } else {
        const unsigned short* xg = (const unsigned short*)Xin + (size_t)b * bstride + n0;
        int px2 = (t & 31) << 1, c0 = t >> 5;
        #pragma unroll 4
        for (int st = 0; st < KK / 8; ++st) {
            int c = c0 + 8 * st;
            unsigned int v = *(const unsigned int*)(xg + (size_t)c * NPIX + px2);
            xs[px2 * LDK + c]       = (unsigned short)(v & 0xFFFFu);
            xs[(px2 + 1) * LDK + c] = (unsigned short)(v >> 16);
        }
    }
    __syncthreads();

    int w  = t >> 6, l = t & 63;
    int wr = w >> 1, wc = w & 1;
    int lr = l & 15, kb = l >> 4;
    int pw = wr * 32;

    bf16x8 afr[KSTEPS][2];
    #pragma unroll
    for (int ks = 0; ks < KSTEPS; ++ks)
        #pragma unroll
        for (int m = 0; m < 2; ++m)
            afr[ks][m] = *(const bf16x8*)&xs[(pw + m * 16 + lr) * LDK + ks * 32 + kb * 8];

    float rsv[2][4], murs[2][4];
    if (LN) {
        #pragma unroll
        for (int m = 0; m < 2; ++m) {
            int pl = pw + m * 16 + kb * 4;
            #pragma unroll
            for (int r = 0; r < 4; ++r) {
                float mv = muL[pl + r];
                rsv[m][r] = rsL[pl + r];
                murs[m][r] = mv * rsv[m][r];
            }
        }
    }

    float zs[2][4], zs2[2][4];
    if constexpr (STATS) {
        #pragma unroll
        for (int m = 0; m < 2; ++m)
            #pragma unroll
            for (int r = 0; r < 4; ++r) { zs[m][r] = 0.f; zs2[m][r] = 0.f; }
    }

    int ocbase = blockIdx.y * MPB;
    #pragma unroll 2
    for (int oc = 0; oc < MPB; ++oc) {
        int ow = ((ocbase + oc) << 6) + wc * 32;
        f32x4 acc[2][2];
        #pragma unroll
        for (int m = 0; m < 2; ++m)
            #pragma unroll
            for (int n = 0; n < 2; ++n) acc[m][n] = (f32x4){0.f, 0.f, 0.f, 0.f};

        #pragma unroll
        for (int kg = 0; kg < KSTEPS; kg += PFG) {
            bf16x8 bfr[PFG][2];
            #pragma unroll
            for (int kk = 0; kk < PFG; ++kk)
                #pragma unroll
                for (int n = 0; n < 2; ++n)
                    bfr[kk][n] = *(const bf16x8*)(Wb + (size_t)(ow + n * 16 + lr) * KK + (kg + kk) * 32 + kb * 8);
            #pragma unroll
            for (int kk = 0; kk < PFG; ++kk)
                #pragma unroll
                for (int m = 0; m < 2; ++m)
                    #pragma unroll
                    for (int n = 0; n < 2; ++n)
                        acc[m][n] = __builtin_amdgcn_mfma_f32_16x16x32_bf16(afr[kg + kk][m], bfr[kk][n], acc[m][n], 0, 0, 0);
        }

        #pragma unroll
        for (int m = 0; m < 2; ++m) {
            int nidx = n0 + pw + m * 16 + kb * 4;
            #pragma unroll
            for (int n = 0; n < 2; ++n) {
                int o = ow + n * 16 + lr;
                float wbv = wb[o];
                float wsv = 0.f; if (LN) wsv = wsum[o];
                size_t obase = (((size_t)b * M + o) << 14) + nidx;
                float rv[4] = {0.f, 0.f, 0.f, 0.f};
                if (RES) {
                    float4 rr = *(const float4*)(resid + obase);
                    rv[0] = rr.x; rv[1] = rr.y; rv[2] = rr.z; rv[3] = rr.w;
                }
                float vo[4];
                #pragma unroll
                for (int r = 0; r < 4; ++r) {
                    float a = acc[m][n][r];
                    float v;
                    if (LN) { float t1 = fmaf(-murs[m][r], wsv, wbv); v = fmaf(rsv[m][r], a, t1); }
                    else    v = a + wbv;
                    if (ACT == 1) v = gelu_f(v);
                    vo[r] = v + rv[r];
                    if constexpr (STATS) {
                        if (oc >= MPB / 2) { zs[m][r] += vo[r]; zs2[m][r] += vo[r] * vo[r]; }
                    }
                }
                if (OBF) {
                    uint2 u;
                    u.x = pack2bf(vo[0], vo[1]);
                    u.y = pack2bf(vo[2], vo[3]);
                    *(uint2*)((unsigned short*)outv + obase) = u;
                } else {
                    float4 f = {vo[0], vo[1], vo[2], vo[3]};
                    *(float4*)((float*)outv + obase) = f;
                }
            }
        }
    }

    if constexpr (STATS) {
        __shared__ float sst[64][2][2];
        #pragma unroll
        for (int m = 0; m < 2; ++m)
            #pragma unroll
            for (int r = 0; r < 4; ++r) {
                float a  = zs[m][r], c2 = zs2[m][r];
                a  += __shfl_xor(a, 1);  a  += __shfl_xor(a, 2);  a  += __shfl_xor(a, 4);  a  += __shfl_xor(a, 8);
                c2 += __shfl_xor(c2, 1); c2 += __shfl_xor(c2, 2); c2 += __shfl_xor(c2, 4); c2 += __shfl_xor(c2, 8);
                if (lr == 0) {
                    int pp = pw + m * 16 + kb * 4 + r;
                    sst[pp][wc][0] = a; sst[pp][wc][1] = c2;
                }
            }
        __syncthreads();
        if (t < 64) {
            float ss  = sst[t][0][0] + sst[t][1][0];
            float ss2 = sst[t][0][1] + sst[t][1][1];
            float invC = 2.f / (float)M;
            float mm = ss * invC;
            smu[(b << 14) + n0 + t] = mm;
            srs[(b << 14) + n0 + t] = rsqrtf(ss2 * invC - mm * mm + 1e-5f);
        }
    }
}

// ============================================================
// MFMA attention (o_win bf16)
// ============================================================
__global__ __launch_bounds__(64) void attn_mfma_k(const unsigned short* __restrict__ qkv,
                                                  const float* __restrict__ rpb,
                                                  const float* __restrict__ temp,
                                                  unsigned short* __restrict__ o_win,
                                                  float* __restrict__ s_win) {
    __shared__ unsigned short p_lds[64 * 72];
    __shared__ float rp[225];
    int wh = blockIdx.x;
    int head = wh % HEADS;
    int bw = wh / HEADS;
    int b = bw / LWIN, l = bw % LWIN;
    int sh = l / LH, sw = l % LH;
    int h0 = sh * STR - 3, w0 = sw * STR - 3;
    int t = threadIdx.x;
    int lr = t & 15, kb = t >> 4;

    for (int i = t; i < 225; i += 64) rp[i] = rpb[i * HEADS + head];
    float tmp = temp[head];

    const size_t qbase = ((size_t)(b * 576 + head * 32)) << 14;
    const unsigned short* qp = qkv + qbase;
    const unsigned short* kp = qkv + qbase + ((size_t)192 << 14);
    const unsigned short* vp = qkv + qbase + ((size_t)384 << 14);

    bf16x8 kf[4], qf[4];
    #pragma unroll
    for (int m = 0; m < 4; ++m) {
        int jp = m * 16 + lr;
        int hh = h0 + (jp >> 3), ww = w0 + (jp & 7);
        bool ok = ((unsigned)hh < 128u) && ((unsigned)ww < 128u);
        int pix = (hh << 7) + ww;
        #pragma unroll
        for (int j = 0; j < 8; ++j) {
            unsigned short kv = 0, qv = 0;
            if (ok) {
                size_t off = ((size_t)(kb * 8 + j) << 14) + pix;
                kv = kp[off];
                qv = qp[off];
            }
            kf[m][j] = (short)kv;
            qf[m][j] = (short)qv;
        }
    }

    f32x4 st[4][4];
    #pragma unroll
    for (int m = 0; m < 4; ++m)
        #pragma unroll
        for (int n = 0; n < 4; ++n) st[m][n] = (f32x4){0.f, 0.f, 0.f, 0.f};
    #pragma unroll
    for (int m = 0; m < 4; ++m)
        #pragma unroll
        for (int n = 0; n < 4; ++n)
            st[m][n] = __builtin_amdgcn_mfma_f32_16x16x32_bf16(kf[m], qf[n], st[m][n], 0, 0, 0);

    bf16x8 vf[2][2];
    #pragma unroll
    for (int np = 0; np < 2; ++np) {
        #pragma unroll
        for (int ks = 0; ks < 2; ++ks) {
            int hh = h0 + ks * 4 + kb;
            bool okr = (unsigned)hh < 128u;
            const unsigned short* vrow = vp + (((size_t)(np * 16 + lr)) << 14) + (hh << 7) + w0;
            #pragma unroll
            for (int j = 0; j < 8; ++j) {
                int ww = w0 + j;
                unsigned short vv = 0;
                if (okr && (unsigned)ww < 128u) vv = vrow[j];
                vf[np][ks][j] = (short)vv;
            }
        }
    }

    __syncthreads();

    #pragma unroll
    for (int n = 0; n < 4; ++n) {
        int i = n * 16 + lr;
        int iyy = i >> 3, ixx = i & 7;
        #pragma unroll
        for (int m = 0; m < 4; ++m) {
            #pragma unroll
            for (int r = 0; r < 4; ++r) {
                int j = m * 16 + kb * 4 + r;
                int dy = iyy - (j >> 3) + 7;
                int dx = ixx - (j & 7) + 7;
                st[m][n][r] = st[m][n][r] * tmp + rp[dy * 15 + dx];
            }
        }
    }

    #pragma unroll
    for (int n = 0; n < 4; ++n) {
        float mx = -1e30f;
        #pragma unroll
        for (int m = 0; m < 4; ++m)
            #pragma unroll
            for (int r = 0; r < 4; ++r) mx = fmaxf(mx, st[m][n][r]);
        mx = fmaxf(mx, __shfl_xor(mx, 16));
        mx = fmaxf(mx, __shfl_xor(mx, 32));
        float s = 0.f;
        #pragma unroll
        for (int m = 0; m < 4; ++m) {
            #pragma unroll
            for (int r = 0; r < 4; ++r) {
                float e = __expf(st[m][n][r] - mx);
                st[m][n][r] = e;
                s += e;
            }
        }
        s += __shfl_xor(s, 16);
        s += __shfl_xor(s, 32);
        int i = n * 16 + lr;
        if (kb == 0) s_win[(size_t)wh * 64 + i] = s;
        #pragma unroll
        for (int m = 0; m < 4; ++m) {
            *(unsigned int*)&p_lds[i * 72 + m * 16 + kb * 4]     = pack2bf(st[m][n][0], st[m][n][1]);
            *(unsigned int*)&p_lds[i * 72 + m * 16 + kb * 4 + 2] = pack2bf(st[m][n][2], st[m][n][3]);
        }
    }

    __syncthreads();

    f32x4 oc[4][2];
    #pragma unroll
    for (int m = 0; m < 4; ++m)
        #pragma unroll
        for (int np = 0; np < 2; ++np) oc[m][np] = (f32x4){0.f, 0.f, 0.f, 0.f};
    #pragma unroll
    for (int ks = 0; ks < 2; ++ks) {
        bf16x8 pa[4];
        #pragma unroll
        for (int m = 0; m < 4; ++m)
            pa[m] = *(const bf16x8*)&p_lds[(m * 16 + lr) * 72 + ks * 32 + kb * 8];
        #pragma unroll
        for (int m = 0; m < 4; ++m)
            #pragma unroll
            for (int np = 0; np < 2; ++np)
                oc[m][np] = __builtin_amdgcn_mfma_f32_16x16x32_bf16(pa[m], vf[np][ks], oc[m][np], 0, 0, 0);
    }

    unsigned short* ob = o_win + (size_t)wh * 2048;
    #pragma unroll
    for (int m = 0; m < 4; ++m) {
        int ibase = m * 16 + kb * 4;
        #pragma unroll
        for (int np = 0; np < 2; ++np) {
            int c = np * 16 + lr;
            #pragma unroll
            for (int r = 0; r < 4; ++r)
                ob[(ibase + r) * 32 + c] = f2bf(oc[m][np][r]);
        }
    }
}

// ============================================================
__device__ __forceinline__ void win_range(int h, int& s0, int& s1) {
    s0 = (h + 1) / 6; if (s0 < 0) s0 = 0;
    s1 = (h + 3) / 6; if (s1 > 21) s1 = 21;
}

__global__ __launch_bounds__(256) void simg_k(const float* __restrict__ s_win, float* __restrict__ s_img) {
    int tid = blockIdx.x * 256 + threadIdx.x;
    if (tid >= B_ * HEADS * NPIX) return;
    int n = tid & (NPIX - 1);
    int bh = tid >> 14;
    int hd = bh % HEADS, b = bh / HEADS;
    int hy = n >> 7, wx = n & 127;
    int sy0, sy1, sx0, sx1;
    win_range(hy, sy0, sy1);
    win_range(wx, sx0, sx1);
    float acc = 0.f;
    for (int sy = sy0; sy <= sy1; ++sy)
        for (int sx = sx0; sx <= sx1; ++sx) {
            int idx = (hy - (sy * 6 - 3)) * 8 + (wx - (sx * 6 - 3));
            acc += s_win[(size_t)((b * LWIN + sy * LH + sx) * HEADS + hd) * 64 + idx];
        }
    s_img[tid] = acc;
}

// ============================================================
// fused fold + proj GEMM: block = 64 px.
// ============================================================
__global__ __launch_bounds__(256) void fold_proj_k(const unsigned short* __restrict__ o_win,
                                                   const float* __restrict__ s_img,
                                                   const unsigned short* __restrict__ Wb,
                                                   const float* __restrict__ wb,
                                                   unsigned short* __restrict__ outv) {
    constexpr int KK = 192, LDK = 200, KSTEPS = 6, PFG = 6, MPB = 3;
    __shared__ unsigned short xs[64 * LDK];

    int t = threadIdx.x;
    int pt = blockIdx.x;
    int b  = pt >> 8;
    int n0 = (pt & 255) << 6;

    // ---- phase 1: fold into LDS ----
    #pragma unroll
    for (int it = 0; it < 6; ++it) {
        int item = it * 256 + t;                 // < 1536
        int px = (item * 2731) >> 16;            // item / 24
        int oct = item - px * 24;
        int n = n0 + px;
        int hd = oct >> 2, c8 = (oct & 3) << 3;
        int hy = n >> 7, wx = n & 127;
        int sy0, sy1, sx0, sx1;
        win_range(hy, sy0, sy1);
        win_range(wx, sx0, sx1);
        float acc[8] = {0.f, 0.f, 0.f, 0.f, 0.f, 0.f, 0.f, 0.f};
        for (int sy = sy0; sy <= sy1; ++sy)
            for (int sx = sx0; sx <= sx1; ++sx) {
                int idx = (hy - (sy * 6 - 3)) * 8 + (wx - (sx * 6 - 3));
                const unsigned short* p = o_win + ((size_t)((b * LWIN + sy * LH + sx) * HEADS + hd) * 2048 + idx * 32 + c8);
                uint4 v = *(const uint4*)p;
                unsigned int arr[4] = {v.x, v.y, v.z, v.w};
                #pragma unroll
                for (int j = 0; j < 4; ++j) {
                    acc[2 * j]     += bf2f((unsigned short)(arr[j] & 0xFFFFu));
                    acc[2 * j + 1] += bf2f((unsigned short)(arr[j] >> 16));
                }
            }
        float inv = __builtin_amdgcn_rcpf(s_img[((b * HEADS + hd) << 14) + n]);
        unsigned int pk[4];
        #pragma unroll
        for (int j = 0; j < 4; ++j)
            pk[j] = pack2bf(acc[2 * j] * inv, acc[2 * j + 1] * inv);
        *(uint4*)&xs[px * LDK + hd * 32 + c8] = make_uint4(pk[0], pk[1], pk[2], pk[3]);
    }
    __syncthreads();

    // ---- phase 2: proj MFMA ----
    int w  = t >> 6, l = t & 63;
    int wr = w >> 1, wc = w & 1;
    int lr = l & 15, kb = l >> 4;
    int pw = wr * 32;

    bf16x8 afr[KSTEPS][2];
    #pragma unroll
    for (int ks = 0; ks < KSTEPS; ++ks)
        #pragma unroll
        for (int m = 0; m < 2; ++m)
            afr[ks][m] = *(const bf16x8*)&xs[(pw + m * 16 + lr) * LDK + ks * 32 + kb * 8];

    #pragma unroll
    for (int oc = 0; oc < MPB; ++oc) {
        int ow = (oc << 6) + wc * 32;
        f32x4 acc2[2][2];
        #pragma unroll
        for (int m = 0; m < 2; ++m)
            #pragma unroll
            for (int n = 0; n < 2; ++n) acc2[m][n] = (f32x4){0.f, 0.f, 0.f, 0.f};

        #pragma unroll
        for (int kg = 0; kg < KSTEPS; kg += PFG) {
            bf16x8 bfr[PFG][2];
            #pragma unroll
            for (int kk = 0; kk < PFG; ++kk)
                #pragma unroll
                for (int n = 0; n < 2; ++n)
                    bfr[kk][n] = *(const bf16x8*)(Wb + (size_t)(ow + n * 16 + lr) * KK + (kg + kk) * 32 + kb * 8);
            #pragma unroll
            for (int kk = 0; kk < PFG; ++kk)
                #pragma unroll
                for (int m = 0; m < 2; ++m)
                    #pragma unroll
                    for (int n = 0; n < 2; ++n)
                        acc2[m][n] = __builtin_amdgcn_mfma_f32_16x16x32_bf16(afr[kg + kk][m], bfr[kk][n], acc2[m][n], 0, 0, 0);
        }

        #pragma unroll
        for (int m = 0; m < 2; ++m) {
            int nidx = n0 + pw + m * 16 + kb * 4;
            #pragma unroll
            for (int n = 0; n < 2; ++n) {
                int o = ow + n * 16 + lr;
                float wbv = wb[o];
                size_t obase = (((size_t)b * 192 + o) << 14) + nidx;
                uint2 u;
                u.x = pack2bf(acc2[m][n][0] + wbv, acc2[m][n][1] + wbv);
                u.y = pack2bf(acc2[m][n][2] + wbv, acc2[m][n][3] + wbv);
                *(uint2*)(outv + obase) = u;
            }
        }
    }
}

// ============================================================
// 2x2 average pooling (input fp32 or bf16, output fp32)
// ============================================================
template <typename TI>
__global__ __launch_bounds__(256) void halve_k(const TI* __restrict__ in, float* __restrict__ out, int Win) {
    int Wo = Win >> 1;
    int tot = B_ * C_ * Wo * Wo;
    int tid = blockIdx.x * 256 + threadIdx.x;
    if (tid >= tot) return;
    int xy = tid % (Wo * Wo);
    int bc = tid / (Wo * Wo);
    int y = xy / Wo, x = xy % Wo;
    const TI* p = in + (size_t)bc * Win * Win + (size_t)(2 * y) * Win + 2 * x;
    float a, bq, c, d;
    if constexpr (sizeof(TI) == 2) {
        a = bf2f(p[0]); bq = bf2f(p[1]); c = bf2f(p[Win]); d = bf2f(p[Win + 1]);
    } else {
        a = p[0]; bq = p[1]; c = p[Win]; d = p[Win + 1];
    }
    out[tid] = 0.25f * (a + bq + c + d);
}

// ============================================================
// fused HFT (po bf16)
// ============================================================
__global__ __launch_bounds__(256) void hft_fused_k(const unsigned short* __restrict__ po, const float* __restrict__ x,
                                                   const float* __restrict__ p2, const float* __restrict__ p4,
                                                   const float* __restrict__ p8, const float* __restrict__ hw,
                                                   const float* __restrict__ hb, float* __restrict__ x1) {
    __shared__ float tile[34 * 133];
    int rt = blockIdx.x, ch = blockIdx.y, b = blockIdx.z;
    int bc = b * C_ + ch;
    int y0 = rt << 5;
    int t = threadIdx.x;
    const unsigned short* pob = po + ((size_t)bc << 14);
    const float* p2b = p2 + ((size_t)bc << 12);
    const float* p4b = p4 + ((size_t)bc << 10);
    const float* p8b = p8 + ((size_t)bc << 8);

    for (int idx = t; idx < 34 * 133; idx += 256) {
        int row = idx / 133, col = idx - row * 133;
        int yy = y0 + row - 1, xw = col - 1;
        float val = 0.f;
        if (col < 130 && (unsigned)yy < 128u && (unsigned)xw < 128u) {
            int nn = (yy << 7) + xw;
            val = 3.f * bf2f(pob[nn])
                - p2b[((yy >> 1) << 6) + (xw >> 1)]
                - p4b[((yy >> 2) << 5) + (xw >> 2)]
                - p8b[((yy >> 3) << 4) + (xw >> 3)];
        }
        tile[idx] = val;
    }
    __syncthreads();

    float wv[9];
    #pragma unroll
    for (int k = 0; k < 9; ++k) wv[k] = hw[ch * 9 + k];
    float hbv = hb[ch];

    int r = t & 31, c0 = (t >> 5) << 4;
    int nbase = ((y0 + r) << 7) + c0;
    const float* xb = x + ((size_t)bc << 14);
    float* x1b = x1 + ((size_t)bc << 14);

    float pov[16], xv[16];
    {
        const uint4* pp4 = (const uint4*)(pob + nbase);
        uint4 a0 = pp4[0], a1 = pp4[1];
        unsigned int arr[8] = {a0.x, a0.y, a0.z, a0.w, a1.x, a1.y, a1.z, a1.w};
        #pragma unroll
        for (int j = 0; j < 8; ++j) {
            pov[2 * j]     = bf2f((unsigned short)(arr[j] & 0xFFFFu));
            pov[2 * j + 1] = bf2f((unsigned short)(arr[j] >> 16));
        }
        #pragma unroll
        for (int j4 = 0; j4 < 4; ++j4) {
            float4 xx = *(const float4*)(xb + nbase + 4 * j4);
            xv[4*j4] = xx.x; xv[4*j4+1] = xx.y; xv[4*j4+2] = xx.z; xv[4*j4+3] = xx.w;
        }
    }
    float res[16];
    #pragma unroll
    for (int j = 0; j < 16; ++j) {
        float acc = hbv;
        #pragma unroll
        for (int dy = 0; dy < 3; ++dy)
            #pragma unroll
            for (int dx = 0; dx < 3; ++dx)
                acc += wv[dy * 3 + dx] * tile[(r + dy) * 133 + c0 + j + dx];
        float sg = __builtin_amdgcn_rcpf(1.f + __expf(-acc));
        res[j] = xv[j] + sg * pov[j];
    }
    #pragma unroll
    for (int j4 = 0; j4 < 4; ++j4) {
        float4 o = {res[4*j4], res[4*j4+1], res[4*j4+2], res[4*j4+3]};
        *(float4*)(x1b + nbase + 4 * j4) = o;
    }
}

// ============================================================
// SimpleGate tiled
// ============================================================
__global__ __launch_bounds__(256) void sgmul_k(unsigned short* __restrict__ z,
                                               const float* __restrict__ mu3, const float* __restrict__ rs3,
                                               const float* __restrict__ sgn_g, const float* __restrict__ sgn_b,
                                               const float* __restrict__ sg_w, const float* __restrict__ sg_b) {
    __shared__ float tile[34 * 133];
    int rt = blockIdx.x, ch = blockIdx.y, b = blockIdx.z;
    int y0 = rt << 5;
    int t = threadIdx.x;
    const unsigned short* zb = z + ((size_t)(b * 768 + 384 + ch) << 14);
    unsigned short* z1p = z + ((size_t)(b * 768 + ch) << 14);
    const float* mub = mu3 + (b << 14);
    const float* rsb = rs3 + (b << 14);
    float g = sgn_g[ch], bb = sgn_b[ch];

    for (int idx = t; idx < 34 * 133; idx += 256) {
        int row = idx / 133, col = idx - row * 133;
        int yy = y0 + row - 1, xw = col - 1;
        float val = 0.f;
        if (col < 130 && (unsigned)yy < 128u && (unsigned)xw < 128u) {
            int nn = (yy << 7) + xw;
            val = (bf2f(zb[nn]) - mub[nn]) * rsb[nn] * g + bb;
        }
        tile[idx] = val;
    }
    __syncthreads();

    float wv[9];
    #pragma unroll
    for (int k = 0; k < 9; ++k) wv[k] = sg_w[ch * 9 + k];
    float sb = sg_b[ch];

    int r = t & 31, c0 = (t >> 5) << 4;
    int nbase = ((y0 + r) << 7) + c0;

    float res[16];
    #pragma unroll
    for (int j = 0; j < 16; ++j) {
        float acc = sb;
        #pragma unroll
        for (int dy = 0; dy < 3; ++dy)
            #pragma unroll
            for (int dx = 0; dx < 3; ++dx)
                acc += wv[dy * 3 + dx] * tile[(r + dy) * 133 + c0 + j + dx];
        res[j] = acc;
    }
    uint4* zp = (uint4*)(z1p + nbase);
    uint4 v0 = zp[0], v1 = zp[1];
    unsigned int arr[8] = {v0.x, v0.y, v0.z, v0.w, v1.x, v1.y, v1.z, v1.w};
    #pragma unroll
    for (int j = 0; j < 8; ++j) {
        float lo = bf2f((unsigned short)(arr[j] & 0xFFFFu)) * res[2 * j];
        float hi = bf2f((unsigned short)(arr[j] >> 16)) * res[2 * j + 1];
        arr[j] = pack2bf(lo, hi);
    }
    zp[0] = make_uint4(arr[0], arr[1], arr[2], arr[3]);
    zp[1] = make_uint4(arr[4], arr[5], arr[6], arr[7]);
}

// ============================================================
extern "C" void kernel_launch(void* const* d_in, const int* in_sizes, int n_in,
                              void* d_out, int out_size, void* d_ws, size_t ws_size,
                              hipStream_t stream) {
    const float* x     = (const float*)d_in[0];
    const float* n1g   = (const float*)d_in[1];
    const float* n1b   = (const float*)d_in[2];
    const float* qkv_w = (const float*)d_in[3];
    const float* qkv_b = (const float*)d_in[4];
    const float* temp  = (const float*)d_in[5];
    const float* rpb   = (const float*)d_in[6];
    const float* proj_w= (const float*)d_in[7];
    const float* proj_b= (const float*)d_in[8];
    const float* hft_w = (const float*)d_in[9];
    const float* hft_b = (const float*)d_in[10];
    const float* n2g   = (const float*)d_in[11];
    const float* n2b   = (const float*)d_in[12];
    const float* fc1_w = (const float*)d_in[13];
    const float* fc1_b = (const float*)d_in[14];
    const float* sgn_g = (const float*)d_in[15];
    const float* sgn_b = (const float*)d_in[16];
    const float* sg_w  = (const float*)d_in[17];
    const float* sg_b  = (const float*)d_in[18];
    const float* fc2_w = (const float*)d_in[19];
    const float* fc2_b = (const float*)d_in[20];
    float* out = (float*)d_out;
    float* w = (float*)d_ws;

    // ---- workspace layout ----
    float* mu3 = w + 262144;   float* rs3 = w + 327680;
    unsigned short* wgb_qkv = (unsigned short*)(w + 393216);
    float* wsum_qkv = w + 448512;  float* wb_qkv = w + 449088;
    unsigned short* wgb_fc1 = (unsigned short*)(w + 449664);
    float* wsum_fc1 = w + 523392;  float* wb_fc1 = w + 524160;
    unsigned short* pwb  = (unsigned short*)(w + 524928);
    unsigned short* f2wb = (unsigned short*)(w + 543360);
    unsigned short* qkvb = (unsigned short*)(w + 6871680);
    unsigned short* proj_out = (unsigned short*)(w + 580224);  // bf16 [b][192][NPIX]
    float* p2 = w + 19454592;  float* p4 = w + 22600320;  float* p8 = w + 23386752;
    unsigned short* o_win = (unsigned short*)(w + 25746048);
    float* s_win = w + 49535616;
    float* s_img = w + 50279040;
    unsigned short* z = (unsigned short*)(w + 25746048);
    float* x1 = w + 50911872;

    // ---- stage A: prep + qkv GEMM (LN in-block from fp32 x) ----
    prep_k<<<3, 256, 0, stream>>>(qkv_w, n1g, n1b, qkv_b, 576, 192, wgb_qkv, wsum_qkv, wb_qkv);
    wcvt_k<<<144, 256, 0, stream>>>(proj_w, pwb, 192 * 192);
    gemm4_k<192, 1, 9, 0, true, false, true, 0><<<dim3(1024, 1), 256, 0, stream>>>(
        wgb_qkv, x, qkvb, wsum_qkv, wb_qkv, nullptr, 576, 192 * NPIX, nullptr, nullptr);
    // ---- stage B: MFMA window attention ----
    attn_mfma_k<<<NWIN * HEADS, 64, 0, stream>>>(qkvb, rpb, temp, o_win, s_win);
    // ---- stage C+D: simg + fused fold/proj -> proj_out bf16 ----
    simg_k<<<1536, 256, 0, stream>>>(s_win, s_img);
    fold_proj_k<<<1024, 256, 0, stream>>>(o_win, s_img, pwb, proj_b, proj_out);
    // ---- stage E: HFT + residual -> x1 (fused) ----
    halve_k<unsigned short><<<12288, 256, 0, stream>>>(proj_out, p2, 128);
    halve_k<float><<<3072, 256, 0, stream>>>(p2, p4, 64);
    halve_k<float><<<768, 256, 0, stream>>>(p4, p8, 32);
    hft_fused_k<<<dim3(4, 192, B_), 256, 0, stream>>>(proj_out, x, p2, p4, p8, hft_w, hft_b, x1);
    // ---- stage F: prep + fc1 GEMM (LN in-block, z2 stats in epilogue) ----
    prep_k<<<3, 256, 0, stream>>>(fc1_w, n2g, n2b, fc1_b, 768, 192, wgb_fc1, wsum_fc1, wb_fc1);
    gemm4_k<192, 1, 12, 1, true, false, true, 1><<<dim3(1024, 1), 256, 0, stream>>>(
        wgb_fc1, x1, z, wsum_fc1, wb_fc1, nullptr, 768, 192 * NPIX, mu3, rs3);
    // ---- stage G: SimpleGate (in-place on z1 rows) ----
    sgmul_k<<<dim3(4, 384, B_), 256, 0, stream>>>(z, mu3, rs3, sgn_g, sgn_b, sg_w, sg_b);
    // ---- stage H: fc2 GEMM (channel-major bf16 in) + residual -> out ----
    wcvt_k<<<288, 256, 0, stream>>>(fc2_w, f2wb, 192 * 384);
    gemm4_k<384, 2, 3, 0, false, true, false, 0><<<dim3(1024, 1), 256, 0, stream>>>(
        f2wb, z, out, nullptr, fc2_b, x1, 192, 768 * NPIX, nullptr, nullptr);
}